// Round 4
// baseline (415.936 us; speedup 1.0000x reference)
//
#include <hip/hip_runtime.h>
#include <math.h>

#define H  2048
#define R  8192        // 4*H gate rows per weight matrix
#define NT 256

__device__ __forceinline__ void fma4(float4& a, const float4 m, const float4 v) {
    a.x = fmaf(m.x, v.x, a.x); a.y = fmaf(m.y, v.y, a.y);
    a.z = fmaf(m.z, v.z, a.z); a.w = fmaf(m.w, v.w, a.w);
}
__device__ __forceinline__ float hsum4(const float4 a) {
    return (a.x + a.y) + (a.z + a.w);
}
__device__ __forceinline__ float sigmoidf_(float v) {
    return 1.f / (1.f + expf(-v));
}

// ---------------------------------------------------------------------------
// Phase 1: all input-independent GEMV rows (268 MB) in ONE kernel.
//   g in [0,R):       xpA[g] = Wi[0][g,:] @ x
//   g in [R,4R):      pre[r] = Wh[l][rr,:] @ h0[l] + bi[r] + bh[r]
// 2 rows per wave -> 16 outstanding float4 row loads + shared vec load;
// 4096 blocks = 4 rounds/CU for stagger. Row pairs never straddle segment
// boundaries (all boundaries are multiples of 8192).
// ---------------------------------------------------------------------------
__global__ __launch_bounds__(NT, 4) void phase1_kernel(
    const float* __restrict__ Wi0,  // [R, H]
    const float* __restrict__ Wh,   // [3R, H] flat
    const float* __restrict__ bi,   // [3R]
    const float* __restrict__ bh,   // [3R]
    const float* __restrict__ x,    // [H]
    const float* __restrict__ h0,   // [3, H]
    float* __restrict__ xpA,        // [R]
    float* __restrict__ pre)        // [3R]
{
    const int w    = blockIdx.x * (NT / 64) + (threadIdx.x >> 6);
    const int lane = threadIdx.x & 63;
    const int g0   = w * 2;                     // first of this wave's 2 rows

    const float* row0;
    const float* vec;
    if (g0 < R) {
        row0 = Wi0 + (size_t)g0 * H;
        vec  = x;
    } else {
        const int r = g0 - R;                   // 0 .. 3R-1
        row0 = Wh + (size_t)r * H;
        vec  = h0 + (r >> 13) * H;              // r / 8192 -> layer
    }

    const float4* r04 = (const float4*)row0;
    const float4* r14 = (const float4*)(row0 + H);
    const float4* v4  = (const float4*)vec;

    float4 a0 = {0.f, 0.f, 0.f, 0.f}, a1 = {0.f, 0.f, 0.f, 0.f};
#pragma unroll
    for (int it = 0; it < 8; ++it) {
        const int idx = it * 64 + lane;
        const float4 v  = v4[idx];
        const float4 m0 = r04[idx];
        const float4 m1 = r14[idx];
        fma4(a0, m0, v);
        fma4(a1, m1, v);
    }

    float s0 = hsum4(a0), s1 = hsum4(a1);
#pragma unroll
    for (int off = 32; off > 0; off >>= 1) {
        s0 += __shfl_down(s0, off);
        s1 += __shfl_down(s1, off);
    }

    if (lane == 0) {
        if (g0 < R) {
            xpA[g0]     = s0;
            xpA[g0 + 1] = s1;
        } else {
            const int r = g0 - R;
            pre[r]     = s0 + bi[r]     + bh[r];
            pre[r + 1] = s1 + bi[r + 1] + bh[r + 1];
        }
    }
}

// ---------------------------------------------------------------------------
// Fused: redundant per-block LSTM update of layer l-1 (h into LDS), then
// xp_out[r] = Wi_l[r,:] @ h.  One row per wave, 2048 blocks (8/CU queued).
// Preamble cost per block: 72 KB L2 reads + ~40 transcendentals/thread.
// ---------------------------------------------------------------------------
__global__ __launch_bounds__(NT, 4) void wix_fused_kernel(
    const float* __restrict__ Wi_l,    // [R, H] this layer's W_ih
    const float* __restrict__ pre_lm1, // [R] Wh@h0 + biases of layer l-1
    const float* __restrict__ xp_lm1,  // [R] Wi@x of layer l-1
    const float* __restrict__ c_lm1,   // [H] c0 of layer l-1
    float* __restrict__ xp_out)        // [R]
{
    __shared__ float hvec[H];          // 8 KB
    const int t = threadIdx.x;

#pragma unroll
    for (int j = t; j < H; j += NT) {
        const float gi = pre_lm1[j]         + xp_lm1[j];
        const float gf = pre_lm1[H + j]     + xp_lm1[H + j];
        const float gg = pre_lm1[2 * H + j] + xp_lm1[2 * H + j];
        const float go = pre_lm1[3 * H + j] + xp_lm1[3 * H + j];
        const float c_new = sigmoidf_(gf) * c_lm1[j] + sigmoidf_(gi) * tanhf(gg);
        hvec[j] = sigmoidf_(go) * tanhf(c_new);
    }
    __syncthreads();

    const int w    = blockIdx.x * (NT / 64) + (t >> 6);   // 0..R-1
    const int lane = t & 63;
    const float4* m4 = (const float4*)(Wi_l + (size_t)w * H);
    const float4* v4 = (const float4*)hvec;

    float4 a = {0.f, 0.f, 0.f, 0.f};
#pragma unroll
    for (int it = 0; it < 8; ++it) {
        const int idx = it * 64 + lane;
        fma4(a, m4[idx], v4[idx]);
    }
    float s = hsum4(a);
#pragma unroll
    for (int off = 32; off > 0; off >>= 1) s += __shfl_down(s, off);
    if (lane == 0) xp_out[w] = s;
}

// Final layer-2 elementwise update -> d_out.
__global__ __launch_bounds__(NT) void final_kernel(
    const float* __restrict__ pre_2,  // [R]
    const float* __restrict__ xpC,    // [R]
    const float* __restrict__ c_2,    // [H]
    float* __restrict__ out)          // [H]
{
    const int j = blockIdx.x * NT + threadIdx.x;
    if (j >= H) return;
    const float gi = pre_2[j]         + xpC[j];
    const float gf = pre_2[H + j]     + xpC[H + j];
    const float gg = pre_2[2 * H + j] + xpC[2 * H + j];
    const float go = pre_2[3 * H + j] + xpC[3 * H + j];
    const float c_new = sigmoidf_(gf) * c_2[j] + sigmoidf_(gi) * tanhf(gg);
    out[j] = sigmoidf_(go) * tanhf(c_new);
}

extern "C" void kernel_launch(void* const* d_in, const int* in_sizes, int n_in,
                              void* d_out, int out_size, void* d_ws, size_t ws_size,
                              hipStream_t stream) {
    const float* x    = (const float*)d_in[0];
    const float* W_ih = (const float*)d_in[1];  // [3, R, H]
    const float* W_hh = (const float*)d_in[2];  // [3, R, H]
    const float* b_ih = (const float*)d_in[3];  // [3R]
    const float* b_hh = (const float*)d_in[4];  // [3R]
    const float* h0   = (const float*)d_in[5];  // [3, H]
    const float* c0   = (const float*)d_in[6];  // [3, H]
    float* out = (float*)d_out;

    float* xpA = (float*)d_ws;   // [R]
    float* xpB = xpA + R;        // [R]
    float* xpC = xpB + R;        // [R]
    float* pre = xpC + R;        // [3R]

    const size_t Ws = (size_t)R * H;

    // Phase 1: Wi[0]@x + all Wh@h0 (+biases). 32768 rows / 2 per wave.
    phase1_kernel<<<4096, NT, 0, stream>>>(W_ih, W_hh, b_ih, b_hh, x, h0,
                                           xpA, pre);

    // Layer-1 GEMV fused with layer-0 update.
    wix_fused_kernel<<<2048, NT, 0, stream>>>(W_ih + Ws, pre, xpA, c0, xpB);

    // Layer-2 GEMV fused with layer-1 update.
    wix_fused_kernel<<<2048, NT, 0, stream>>>(W_ih + 2 * Ws, pre + R, xpB,
                                              c0 + H, xpC);

    // Final layer-2 update.
    final_kernel<<<H / NT, NT, 0, stream>>>(pre + 2 * R, xpC, c0 + 2 * H, out);
}